// Round 1
// baseline (123.775 us; speedup 1.0000x reference)
//
#include <hip/hip_runtime.h>

#define B_    1024
#define T_    256
#define C_    128
#define LMAX  32
#define NEGV  -1e9f

// logaddexp in fp32 with fast HW transcendentals
__device__ __forceinline__ float laddexp(float p, float q) {
    float m = fmaxf(p, q);
    float d = fabsf(p - q);
    return m + __logf(1.0f + __expf(-d));
}

// ---------------------------------------------------------------------------
// Kernel A: per-row log-sum-exp of y_pred[row, 0..127]  (one wave per row)
// ---------------------------------------------------------------------------
__global__ void __launch_bounds__(256) lse_kernel(const float* __restrict__ yp,
                                                  float* __restrict__ lse) {
    int row  = (int)((blockIdx.x * blockDim.x + threadIdx.x) >> 6);
    int lane = threadIdx.x & 63;
    if (row >= B_ * T_) return;
    const float* x = yp + (size_t)row * C_;
    float a = x[lane];
    float b = x[lane + 64];
    float m = fmaxf(a, b);
    #pragma unroll
    for (int off = 32; off; off >>= 1) m = fmaxf(m, __shfl_xor(m, off));
    float s = __expf(a - m) + __expf(b - m);
    #pragma unroll
    for (int off = 32; off; off >>= 1) s += __shfl_xor(s, off);
    if (lane == 0) lse[row] = m + __logf(s);
}

// ---------------------------------------------------------------------------
// Kernel B: CTC forward recursion, one 64-lane wave per batch example.
// lane s (0..63) holds alpha[s]; alpha[64] replicated in all lanes (a64).
// ---------------------------------------------------------------------------
__global__ void __launch_bounds__(64) ctc_fwd_kernel(const float* __restrict__ yp,
                                                     const int* __restrict__ yt,
                                                     const float* __restrict__ lse,
                                                     float* __restrict__ loss) {
    int b    = blockIdx.x;
    int lane = threadIdx.x;          // 0..63
    const int* lab = yt + b * LMAX;

    // label_len = count(lab != 99)
    int myl = (lane < LMAX) ? lab[lane] : 99;
    unsigned long long bal = __ballot(lane < LMAX && myl != 99);
    int L = __popcll(bal);

    // extended-label class + skip flag for state s = lane
    int  j      = lane >> 1;
    int  labj   = lab[j & (LMAX - 1)];
    int  labjm1 = (j > 0) ? lab[j - 1] : (C_ - 1);   // pad with blank
    bool odd    = (lane & 1) != 0;
    int  cls    = odd ? labj : (C_ - 1);
    bool skip   = odd && (labj != labjm1);
    if (cls < 0) cls = 0;
    if (cls > C_ - 1) cls = C_ - 1;

    const float* xb = yp + (size_t)b * T_ * C_;
    const float* lr = lse + b * T_;

    // t = 0 init
    float lse_c = lr[0];
    float x_c   = xb[cls];
    float lp0   = x_c - lse_c;
    float a     = NEGV;
    if (lane == 0) a = lp0;
    if (lane == 1 && L > 0) a = lp0;
    float a64 = NEGV;

    // prefetch t = 1
    float x_n   = xb[C_ + cls];
    float lse_n = lr[1];

    for (int t = 1; t < T_; ++t) {
        float lp_t = x_n - lse_n;
        if (t + 1 < T_) {                      // prefetch t+1
            x_n   = xb[(size_t)(t + 1) * C_ + cls];
            lse_n = lr[t + 1];
        }
        float am1 = __shfl_up(a, 1);
        float am2 = __shfl_up(a, 2);
        float a63 = __shfl(a, 63);
        if (lane < 1) am1 = NEGV;
        if (lane < 2) am2 = NEGV;
        float r = laddexp(a, am1);
        if (skip) r = laddexp(r, am2);
        float lpb = __shfl(lp_t, 0);           // blank lp (lane 0 holds it)
        float r64 = laddexp(a64, a63);
        a   = r + lp_t;
        a64 = r64 + lpb;
    }

    int idx_last  = 2 * L;                               // <= 64
    float a_blank = (idx_last >= 64) ? a64 : __shfl(a, idx_last);
    int il        = idx_last - 1;
    if (il < 0) il = 0;
    float a_label = __shfl(a, il);
    if (L == 0) a_label = NEGV;
    float lb = -laddexp(a_blank, a_label);
    if (lane == 0) loss[b] = lb;
}

// ---------------------------------------------------------------------------
// Kernel C: mean of per-example losses -> d_out[0]
// ---------------------------------------------------------------------------
__global__ void __launch_bounds__(64) reduce_kernel(const float* __restrict__ loss,
                                                    float* __restrict__ out) {
    int lane = threadIdx.x;
    float s = 0.f;
    for (int k = lane; k < B_; k += 64) s += loss[k];
    #pragma unroll
    for (int off = 32; off; off >>= 1) s += __shfl_xor(s, off);
    if (lane == 0) out[0] = s * (1.0f / B_);
}

extern "C" void kernel_launch(void* const* d_in, const int* in_sizes, int n_in,
                              void* d_out, int out_size, void* d_ws, size_t ws_size,
                              hipStream_t stream) {
    const int*   yt  = (const int*)d_in[0];    // y_true [1024, 32] int32
    const float* yp  = (const float*)d_in[1];  // y_pred [1024, 256, 128] f32
    float*       out = (float*)d_out;          // scalar mean loss
    float*       lse  = (float*)d_ws;          // [B*T] floats
    float*       loss = lse + (size_t)B_ * T_; // [B] floats

    lse_kernel<<<(B_ * T_) / 4, 256, 0, stream>>>(yp, lse);
    ctc_fwd_kernel<<<B_, 64, 0, stream>>>(yp, yt, lse, loss);
    reduce_kernel<<<1, 64, 0, stream>>>(loss, out);
}

// Round 2
// 91.648 us; speedup vs baseline: 1.3506x; 1.3506x over previous
//
#include <hip/hip_runtime.h>

#define B_    1024
#define T_    256
#define C_    128
#define LMAX  32
#define NEGV  -1e9f
#define K_    16

// 2-way logaddexp (epilogue only)
__device__ __forceinline__ float laddexp(float p, float q) {
    float m = fmaxf(p, q);
    float d = fabsf(p - q);
    return m + __logf(1.0f + __expf(-d));
}

// ---------------------------------------------------------------------------
// Kernel A: per-row log-sum-exp, float4 loads, 2 rows per wave
// ---------------------------------------------------------------------------
__global__ void __launch_bounds__(256) lse_kernel(const float* __restrict__ yp,
                                                  float* __restrict__ lse) {
    int wave = threadIdx.x >> 6;
    int lane = threadIdx.x & 63;
    int half = lane >> 5;          // which of the 2 rows this half-wave owns
    int li   = lane & 31;
    int row  = blockIdx.x * 8 + wave * 2 + half;
    const float4* x = (const float4*)(yp + (size_t)row * C_) + li;
    float4 v = *x;
    float m = fmaxf(fmaxf(v.x, v.y), fmaxf(v.z, v.w));
    #pragma unroll
    for (int off = 16; off; off >>= 1) m = fmaxf(m, __shfl_xor(m, off));
    float s = __expf(v.x - m) + __expf(v.y - m) + __expf(v.z - m) + __expf(v.w - m);
    #pragma unroll
    for (int off = 16; off; off >>= 1) s += __shfl_xor(s, off);
    if (li == 0) lse[row] = m + __logf(s);
}

// ---------------------------------------------------------------------------
// Kernel B: CTC forward, one wave per example, 16-deep double-buffered
// register prefetch + 3-way fused log-sum-exp per step.
// ---------------------------------------------------------------------------
#define LOADC(XBUF, LBUF, BASE) do {                                         \
    _Pragma("unroll")                                                        \
    for (int k = 0; k < K_; ++k) {                                           \
        XBUF[k] = xb[(size_t)((BASE) + k) * C_];                             \
        LBUF[k] = lrb[(BASE) + k];                                           \
    }                                                                        \
} while (0)

#define STEP(LP) do {                                                        \
    float am1 = __shfl_up(a, 1);                                             \
    float am2 = __shfl_up(a, 2);                                             \
    float a63 = __shfl(a, 63);                                               \
    if (lane < 1) am1 = NEGV;                                                \
    float am2e = (skip && lane >= 2) ? am2 : NEGV;                           \
    float m  = fmaxf(fmaxf(a, am1), am2e);                                   \
    float s  = __expf(a - m) + __expf(am1 - m) + __expf(am2e - m);           \
    float r  = m + __logf(s);                                                \
    float lpb = __shfl((LP), 0);                                             \
    float m2  = fmaxf(a64, a63);                                             \
    float r64 = m2 + __logf(__expf(a64 - m2) + __expf(a63 - m2));            \
    a   = r + (LP);                                                          \
    a64 = r64 + lpb;                                                         \
} while (0)

__global__ void __launch_bounds__(64) ctc_fwd_kernel(const float* __restrict__ yp,
                                                     const int* __restrict__ yt,
                                                     const float* __restrict__ lse,
                                                     float* __restrict__ loss) {
    int b    = blockIdx.x;
    int lane = threadIdx.x;
    const int* lab = yt + b * LMAX;

    int myl = (lane < LMAX) ? lab[lane] : 99;
    unsigned long long bal = __ballot(lane < LMAX && myl != 99);
    int L = __popcll(bal);

    int  j      = lane >> 1;
    int  labj   = lab[j & (LMAX - 1)];
    int  labjm1 = (j > 0) ? lab[j - 1] : (C_ - 1);
    bool odd    = (lane & 1) != 0;
    int  cls    = odd ? labj : (C_ - 1);
    bool skip   = odd && (labj != labjm1);
    if (cls < 0) cls = 0;
    if (cls > C_ - 1) cls = C_ - 1;

    const float* xb  = yp + (size_t)b * T_ * C_ + cls;   // per-lane column base
    const float* lrb = lse + b * T_;

    float xA[K_], lA[K_], xB[K_], lB[K_];
    LOADC(xA, lA, 0);
    LOADC(xB, lB, K_);

    float a, a64 = NEGV;
    {   // chunk 0: k=0 is the t=0 init
        float lp0 = xA[0] - lA[0];
        a = (lane == 0 || (lane == 1 && L > 0)) ? lp0 : NEGV;
        #pragma unroll
        for (int k = 1; k < K_; ++k) { float lp = xA[k] - lA[k]; STEP(lp); }
    }
    for (int c = 1; c <= 13; c += 2) {
        LOADC(xA, lA, (c + 1) * K_);
        #pragma unroll
        for (int k = 0; k < K_; ++k) { float lp = xB[k] - lB[k]; STEP(lp); }
        LOADC(xB, lB, (c + 2) * K_);
        #pragma unroll
        for (int k = 0; k < K_; ++k) { float lp = xA[k] - lA[k]; STEP(lp); }
    }
    // final chunk 15 (in B)
    #pragma unroll
    for (int k = 0; k < K_; ++k) { float lp = xB[k] - lB[k]; STEP(lp); }

    int idx_last  = 2 * L;
    float a_blank = (idx_last >= 64) ? a64 : __shfl(a, idx_last);
    int il        = idx_last - 1;
    if (il < 0) il = 0;
    float a_label = __shfl(a, il);
    if (L == 0) a_label = NEGV;
    float lb = -laddexp(a_blank, a_label);
    if (lane == 0) loss[b] = lb;
}

// ---------------------------------------------------------------------------
// Kernel C: mean of per-example losses -> d_out[0]
// ---------------------------------------------------------------------------
__global__ void __launch_bounds__(64) reduce_kernel(const float* __restrict__ loss,
                                                    float* __restrict__ out) {
    int lane = threadIdx.x;
    float s = 0.f;
    for (int k = lane; k < B_; k += 64) s += loss[k];
    #pragma unroll
    for (int off = 32; off; off >>= 1) s += __shfl_xor(s, off);
    if (lane == 0) out[0] = s * (1.0f / B_);
}

extern "C" void kernel_launch(void* const* d_in, const int* in_sizes, int n_in,
                              void* d_out, int out_size, void* d_ws, size_t ws_size,
                              hipStream_t stream) {
    const int*   yt  = (const int*)d_in[0];
    const float* yp  = (const float*)d_in[1];
    float*       out = (float*)d_out;
    float*       lse  = (float*)d_ws;
    float*       loss = lse + (size_t)B_ * T_;

    lse_kernel<<<(B_ * T_) / 8, 256, 0, stream>>>(yp, lse);
    ctc_fwd_kernel<<<B_, 64, 0, stream>>>(yp, yt, lse, loss);
    reduce_kernel<<<1, 64, 0, stream>>>(loss, out);
}

// Round 3
// 87.304 us; speedup vs baseline: 1.4178x; 1.0498x over previous
//
#include <hip/hip_runtime.h>

#define B_    1024
#define T_    256
#define C_    128
#define LMAX  32
#define NEGV  -1e9f
#define K_    16

__device__ __forceinline__ float laddexp(float p, float q) {
    float m = fmaxf(p, q);
    float d = fabsf(p - q);
    return m + __logf(1.0f + __expf(-d));
}

// DPP wave_shr:1  — dest[lane] = src[lane-1], lane 0 keeps `old` (NEGV)
__device__ __forceinline__ float dpp_shr1(float v) {
    int r = __builtin_amdgcn_update_dpp(__float_as_int(NEGV), __float_as_int(v),
                                        0x138, 0xF, 0xF, false);
    return __int_as_float(r);
}
__device__ __forceinline__ float readlane63(float v) {
    return __int_as_float(__builtin_amdgcn_readlane(__float_as_int(v), 63));
}
__device__ __forceinline__ float readlane0(float v) {
    return __int_as_float(__builtin_amdgcn_readfirstlane(__float_as_int(v)));
}

// ---------------------------------------------------------------------------
// Kernel A: per-row log-sum-exp, float4 loads, 2 rows per wave
// ---------------------------------------------------------------------------
__global__ void __launch_bounds__(256) lse_kernel(const float* __restrict__ yp,
                                                  float* __restrict__ lse) {
    int wave = threadIdx.x >> 6;
    int lane = threadIdx.x & 63;
    int half = lane >> 5;
    int li   = lane & 31;
    int row  = blockIdx.x * 8 + wave * 2 + half;
    const float4* x = (const float4*)(yp + (size_t)row * C_) + li;
    float4 v = *x;
    float m = fmaxf(fmaxf(v.x, v.y), fmaxf(v.z, v.w));
    #pragma unroll
    for (int off = 16; off; off >>= 1) m = fmaxf(m, __shfl_xor(m, off));
    float s = __expf(v.x - m) + __expf(v.y - m) + __expf(v.z - m) + __expf(v.w - m);
    #pragma unroll
    for (int off = 16; off; off >>= 1) s += __shfl_xor(s, off);
    if (li == 0) lse[row] = m + __logf(s);
}

// ---------------------------------------------------------------------------
// Kernel B: CTC forward. One wave per example. DPP lane-shifts (runtime-
// verified, shfl fallback), readlane broadcasts, 16-deep dbuf prefetch.
// ---------------------------------------------------------------------------
template<bool DPP>
__device__ __forceinline__ void ctc_step(float& a, float& a64, float lp,
                                         int lane, bool skip) {
    float am1, am2;
    if constexpr (DPP) {
        am1 = dpp_shr1(a);
        am2 = dpp_shr1(am1);
    } else {
        float s1 = __shfl_up(a, 1);
        float s2 = __shfl_up(a, 2);
        am1 = (lane < 1) ? NEGV : s1;
        am2 = (lane < 2) ? NEGV : s2;
    }
    float a63  = readlane63(a);
    float am2e = skip ? am2 : NEGV;
    float m    = fmaxf(fmaxf(a, am1), am2e);
    float r    = m + __logf(__expf(a - m) + __expf(am1 - m) + __expf(am2e - m));
    float lpb  = readlane0(lp);
    float m2   = fmaxf(a64, a63);
    float r64  = m2 + __logf(__expf(a64 - m2) + __expf(a63 - m2));
    a   = r + lp;
    a64 = r64 + lpb;
}

template<bool DPP>
__device__ __forceinline__ float ctc_body(const float* __restrict__ xb,
                                          const float* __restrict__ lrb,
                                          int lane, bool skip, int L) {
    float xA[K_], lA[K_], xB[K_], lB[K_];
    #pragma unroll
    for (int k = 0; k < K_; ++k) { xA[k] = xb[(size_t)k * C_];        lA[k] = lrb[k]; }
    #pragma unroll
    for (int k = 0; k < K_; ++k) { xB[k] = xb[(size_t)(K_ + k) * C_]; lB[k] = lrb[K_ + k]; }

    float lp0 = xA[0] - lA[0];
    float a   = (lane == 0 || (lane == 1 && L > 0)) ? lp0 : NEGV;
    float a64 = NEGV;
    #pragma unroll
    for (int k = 1; k < K_; ++k) ctc_step<DPP>(a, a64, xA[k] - lA[k], lane, skip);

    for (int c = 1; c <= 13; c += 2) {
        const float* xpa = xb  + (size_t)(c + 1) * K_ * C_;
        const float* lpa = lrb + (c + 1) * K_;
        #pragma unroll
        for (int k = 0; k < K_; ++k) { xA[k] = xpa[(size_t)k * C_]; lA[k] = lpa[k]; }
        #pragma unroll
        for (int k = 0; k < K_; ++k) ctc_step<DPP>(a, a64, xB[k] - lB[k], lane, skip);

        const float* xpb = xb  + (size_t)(c + 2) * K_ * C_;
        const float* lpb = lrb + (c + 2) * K_;
        #pragma unroll
        for (int k = 0; k < K_; ++k) { xB[k] = xpb[(size_t)k * C_]; lB[k] = lpb[k]; }
        #pragma unroll
        for (int k = 0; k < K_; ++k) ctc_step<DPP>(a, a64, xA[k] - lA[k], lane, skip);
    }
    #pragma unroll
    for (int k = 0; k < K_; ++k) ctc_step<DPP>(a, a64, xB[k] - lB[k], lane, skip);

    int idx_last  = 2 * L;
    float a_blank = (idx_last >= 64) ? a64 : __shfl(a, idx_last);
    int il        = idx_last - 1; if (il < 0) il = 0;
    float a_label = __shfl(a, il);
    if (L == 0) a_label = NEGV;
    return -laddexp(a_blank, a_label);
}

__global__ void __launch_bounds__(64) ctc_fwd_kernel(const float* __restrict__ yp,
                                                     const int* __restrict__ yt,
                                                     const float* __restrict__ lse,
                                                     float* __restrict__ loss) {
    int b    = blockIdx.x;
    int lane = threadIdx.x;
    const int* lab = yt + b * LMAX;

    int myl = (lane < LMAX) ? lab[lane] : 99;
    unsigned long long bal = __ballot(lane < LMAX && myl != 99);
    int L = __popcll(bal);

    int  j      = lane >> 1;
    int  labj   = lab[j & (LMAX - 1)];
    int  labjm1 = (j > 0) ? lab[j - 1] : (C_ - 1);
    bool odd    = (lane & 1) != 0;
    int  cls    = odd ? labj : (C_ - 1);
    bool skip   = odd && (labj != labjm1);
    if (cls < 0) cls = 0;
    if (cls > C_ - 1) cls = C_ - 1;

    const float* xb  = yp  + (size_t)b * T_ * C_ + cls;
    const float* lrb = lse + b * T_;

    // runtime DPP direction probe (wave-uniform branch, ~free)
    int probe  = __builtin_amdgcn_update_dpp(-1, lane, 0x138, 0xF, 0xF, false);
    bool dppok = __all(probe == ((lane == 0) ? -1 : lane - 1)) != 0;

    float lb = dppok ? ctc_body<true >(xb, lrb, lane, skip, L)
                     : ctc_body<false>(xb, lrb, lane, skip, L);
    if (lane == 0) loss[b] = lb;
}

// ---------------------------------------------------------------------------
// Kernel C: mean of per-example losses -> d_out[0]
// ---------------------------------------------------------------------------
__global__ void __launch_bounds__(256) reduce_kernel(const float* __restrict__ loss,
                                                     float* __restrict__ out) {
    __shared__ float ps[4];
    int t = threadIdx.x;
    float4 v = ((const float4*)loss)[t];
    float s = v.x + v.y + v.z + v.w;
    #pragma unroll
    for (int off = 32; off; off >>= 1) s += __shfl_xor(s, off);
    if ((t & 63) == 0) ps[t >> 6] = s;
    __syncthreads();
    if (t == 0) out[0] = (ps[0] + ps[1] + ps[2] + ps[3]) * (1.0f / B_);
}

extern "C" void kernel_launch(void* const* d_in, const int* in_sizes, int n_in,
                              void* d_out, int out_size, void* d_ws, size_t ws_size,
                              hipStream_t stream) {
    const int*   yt  = (const int*)d_in[0];
    const float* yp  = (const float*)d_in[1];
    float*       out = (float*)d_out;
    float*       lse  = (float*)d_ws;
    float*       loss = lse + (size_t)B_ * T_;

    lse_kernel<<<(B_ * T_) / 8, 256, 0, stream>>>(yp, lse);
    ctc_fwd_kernel<<<B_, 64, 0, stream>>>(yp, yt, lse, loss);
    reduce_kernel<<<1, 256, 0, stream>>>(loss, out);
}